// Round 3
// baseline (232.149 us; speedup 1.0000x reference)
//
#include <hip/hip_runtime.h>
#include <hip/hip_bf16.h>

// LSTM cell, B=65536, I=H=128, fp32 I/O. R7: convert-on-stage fragment LDS.
// 512 blocks x 512 threads (8 waves), 4 tiles of 32 batch rows per block.
// Staging wave w converts A fp32->bf16 and writes the finished MFMA A-fragment
// for ks=w (frag = 1 KB at (mt*8+ks)*1024); compute reads ONE linear
// ds_read_b128 per (mt,ks) -- no swizzle, no per-wave cvt duplication
// (A-frags are identical across waves; R6 converted them 8x each).
// One __syncthreads per tile: order per wave is W(t) bar R(t) E(t); for any
// waves X,Y:  X.R(t) < X.W(t+1) < bar(t+1) < Y.R(t+1) < Y.W(t+2), so all
// reads of buf[t&1] complete before it is rewritten at t+2. Weights: ks 0-3
// pinned in regs (64 regs, AGPR-eligible), ks 4-7 streamed from L2 per tile
// (keeps arch VGPR <=128 for 2 blocks/CU).

typedef short s16x8 __attribute__((ext_vector_type(8)));
typedef float f32x4 __attribute__((ext_vector_type(4)));

__device__ __forceinline__ short f2bf(float f) {
    __hip_bfloat16 h = __float2bfloat16(f);
    return __builtin_bit_cast(short, h);
}
__device__ __forceinline__ float sigm(float x) { return 1.0f / (1.0f + __expf(-x)); }
__device__ __forceinline__ float tanh_f(float x) { return 1.0f - 2.0f / (1.0f + __expf(2.0f * x)); }

// ---- kernel 1: repack 8 fp32 weight mats -> bf16 MFMA-fragment order ----
// Frag fi = (jt16*4 + g)*8 + ks  (256 frags x 1 KB). Lane l of frag holds
// W[g][j = jt16*16 + (l&15)][k = ks*32 + (l>>4)*8 .. +8), k<128 from W_x,
// k>=128 from W_h (k-128). Element order: v[0..3]=k+0..3, v[4..7]=k+4..7.
__global__ __launch_bounds__(256)
void repack_weights(const float* __restrict__ Wii, const float* __restrict__ Whi,
                    const float* __restrict__ Wif, const float* __restrict__ Whf,
                    const float* __restrict__ Wig, const float* __restrict__ Whg,
                    const float* __restrict__ Wio, const float* __restrict__ Who,
                    short* __restrict__ ws)
{
    const int t   = blockIdx.x * 256 + threadIdx.x;   // 16384 threads
    const int fi  = t >> 6;
    const int l   = t & 63;
    const int ks  = fi & 7;
    const int g   = (fi >> 3) & 3;
    const int jt  = fi >> 5;
    const int j   = jt * 16 + (l & 15);
    const int k   = ks * 32 + (l >> 4) * 8;

    const float* wx = (g == 0) ? Wii : (g == 1) ? Wif : (g == 2) ? Wig : Wio;
    const float* wh = (g == 0) ? Whi : (g == 1) ? Whf : (g == 2) ? Whg : Who;
    const float* src = (k < 128) ? (wx + (size_t)j * 128 + k)
                                 : (wh + (size_t)j * 128 + (k - 128));
    f32x4 a = *(const f32x4*)src;
    f32x4 b = *(const f32x4*)(src + 4);
    s16x8 v;
#pragma unroll
    for (int q = 0; q < 4; ++q) { v[q] = f2bf(a[q]); v[4 + q] = f2bf(b[q]); }
    *(s16x8*)(ws + (size_t)t * 8) = v;
}

// ---- kernel 2: main fused LSTM ----
__global__ __launch_bounds__(512, 4)
void lstm_cell_kernel(const float* __restrict__ X,
                      const float* __restrict__ H,
                      const float* __restrict__ C,
                      const float* __restrict__ Bi, const float* __restrict__ Bf,
                      const float* __restrict__ Bg, const float* __restrict__ Bo,
                      const short* __restrict__ WS,
                      float* __restrict__ OutH,
                      float* __restrict__ OutC)
{
    __shared__ __align__(16) char sA[32768];   // 2 bufs x 16 frags x 1 KB

    const int tid = threadIdx.x;
    const int l   = tid & 63;
    const int w   = tid >> 6;          // 0..7
    const int lj  = l & 15;
    const int lq  = l >> 4;
    const int jw  = w * 16 + lj;       // this lane's j (all 4 gates)
    const int tile0 = blockIdx.x * 4;

    // pinned weight frags, ks 0..3 (16 frags = 64 regs, AGPR-eligible)
    const short* wsw = WS + (size_t)(w * 4) * 8 * 512 + (size_t)l * 8;
    s16x8 wlo[4][4];
#pragma unroll
    for (int g = 0; g < 4; ++g)
#pragma unroll
        for (int ks = 0; ks < 4; ++ks)
            wlo[g][ks] = *(const s16x8*)(wsw + (size_t)(g * 8 + ks) * 512);

    const float bi  = Bi[jw];
    const float bfv = Bf[jw];
    const float bg  = Bg[jw];
    const float bo  = Bo[jw];

    // staging role of this thread: fragment ks = w; mt = 0,1.
    // A = [x | h]: waves 0-3 stage x cols w*32.., waves 4-7 stage h cols (w-4)*32..
    const float* sbase = (w < 4) ? X : H;
    const int    colr  = (w & 3) * 32 + lq * 8;

    f32x4 sa[2][2], sb[2][2];          // [buf][mt], statically indexed (full unroll)

    // prologue: issue A loads for tile 0
    {
        const int B0 = tile0 * 32;
#pragma unroll
        for (int mt = 0; mt < 2; ++mt) {
            const float* p = sbase + (size_t)(B0 + mt * 16 + lj) * 128 + colr;
            sa[0][mt] = *(const f32x4*)p;
            sb[0][mt] = *(const f32x4*)(p + 4);
        }
    }

#pragma unroll
    for (int t = 0; t < 4; ++t) {
        char* buf = sA + (t & 1) * 16384;

        // ---- W: convert + write this thread's fragment slots (ks = w) ----
#pragma unroll
        for (int mt = 0; mt < 2; ++mt) {
            s16x8 v;
#pragma unroll
            for (int q = 0; q < 4; ++q) {
                v[q]     = f2bf(sa[t & 1][mt][q]);
                v[4 + q] = f2bf(sb[t & 1][mt][q]);
            }
            *(s16x8*)(buf + (mt * 8 + w) * 1024 + l * 16) = v;
        }
        __syncthreads();

        // ---- issue next-tile A loads (consumed in W(t+1), after next bar) ----
        if (t < 3) {
            const int B0n = (tile0 + t + 1) * 32;
#pragma unroll
            for (int mt = 0; mt < 2; ++mt) {
                const float* p = sbase + (size_t)(B0n + mt * 16 + lj) * 128 + colr;
                sa[(t + 1) & 1][mt] = *(const f32x4*)p;
                sb[(t + 1) & 1][mt] = *(const f32x4*)(p + 4);
            }
        }

        // ---- stream weight frags ks 4..7 (L2-hot; used ~500cy later) ----
        s16x8 whi[4][4];
#pragma unroll
        for (int g = 0; g < 4; ++g)
#pragma unroll
            for (int ks = 0; ks < 4; ++ks)
                whi[g][ks] = *(const s16x8*)(wsw + (size_t)(g * 8 + 4 + ks) * 512);

        // ---- C prefetch for this tile (used in epilogue) ----
        const int B0 = (tile0 + t) * 32;
        float cpv[8];
#pragma unroll
        for (int mt = 0; mt < 2; ++mt)
#pragma unroll
            for (int r = 0; r < 4; ++r)
                cpv[mt * 4 + r] = C[(size_t)(B0 + mt * 16 + lq * 4 + r) * 128 + jw];

        // ---- R: one linear frag read per (mt,ks) + MFMA ----
        f32x4 acc[2][4];
#pragma unroll
        for (int mt = 0; mt < 2; ++mt)
#pragma unroll
            for (int g = 0; g < 4; ++g)
                acc[mt][g] = (f32x4){0.f, 0.f, 0.f, 0.f};

#pragma unroll
        for (int ks = 0; ks < 8; ++ks) {
            const s16x8 af0 = *(const s16x8*)(buf + (0 * 8 + ks) * 1024 + l * 16);
            const s16x8 af1 = *(const s16x8*)(buf + (1 * 8 + ks) * 1024 + l * 16);
#pragma unroll
            for (int g = 0; g < 4; ++g) {
                const s16x8 bfrag = (ks < 4) ? wlo[g][ks] : whi[g][ks - 4];
                acc[0][g] = __builtin_amdgcn_mfma_f32_16x16x32_bf16(af0, bfrag, acc[0][g], 0, 0, 0);
                acc[1][g] = __builtin_amdgcn_mfma_f32_16x16x32_bf16(af1, bfrag, acc[1][g], 0, 0, 0);
            }
        }

        // ---- E: all 4 gates of (b,j) in-lane; C from prefetch ----
#pragma unroll
        for (int mt = 0; mt < 2; ++mt) {
#pragma unroll
            for (int r = 0; r < 4; ++r) {
                const int b = B0 + mt * 16 + lq * 4 + r;   // C/D: row=(lane>>4)*4+reg
                const size_t idx = (size_t)b * 128 + jw;
                const float ia = acc[mt][0][r] + bi;
                const float fa = acc[mt][1][r] + bfv;
                const float ga = acc[mt][2][r] + bg;
                const float oa = acc[mt][3][r] + bo;
                const float it = sigm(ia);
                const float ft = sigm(fa);
                const float gt = tanh_f(ga);
                const float ot = sigm(oa);
                const float co = cpv[mt * 4 + r];
                const float cn = ft * co + it * gt;
                const float hn = ot * tanh_f(cn);
                OutH[idx] = hn;
                OutC[idx] = cn;
            }
        }
    }
}

extern "C" void kernel_launch(void* const* d_in, const int* in_sizes, int n_in,
                              void* d_out, int out_size, void* d_ws, size_t ws_size,
                              hipStream_t stream) {
    const float* X   = (const float*)d_in[0];
    const float* H   = (const float*)d_in[1];
    const float* C   = (const float*)d_in[2];
    const float* Wii = (const float*)d_in[3];
    const float* Whi = (const float*)d_in[4];
    const float* Bi  = (const float*)d_in[5];
    const float* Wif = (const float*)d_in[6];
    const float* Whf = (const float*)d_in[7];
    const float* Bf  = (const float*)d_in[8];
    const float* Wig = (const float*)d_in[9];
    const float* Whg = (const float*)d_in[10];
    const float* Bg  = (const float*)d_in[11];
    const float* Wio = (const float*)d_in[12];
    const float* Who = (const float*)d_in[13];
    const float* Bo  = (const float*)d_in[14];

    short* ws = (short*)d_ws;   // 256 KB bf16 fragment-ordered weights

    hipLaunchKernelGGL(repack_weights, dim3(64), dim3(256), 0, stream,
                       Wii, Whi, Wif, Whf, Wig, Whg, Wio, Who, ws);

    float* OutH = (float*)d_out;
    float* OutC = OutH + (size_t)65536 * 128;

    hipLaunchKernelGGL(lstm_cell_kernel, dim3(512), dim3(512), 0, stream,
                       X, H, C, Bi, Bf, Bg, Bo, ws, OutH, OutC);
}

// Round 5
// 193.800 us; speedup vs baseline: 1.1979x; 1.1979x over previous
//
#include <hip/hip_runtime.h>
#include <hip/hip_bf16.h>

// LSTM cell, B=65536, I=H=128, fp32 I/O. R8b: one-tile blocks + streamed
// weights (identical to R8; previous round was an infra container failure).
// 2048 blocks x 512 threads (8 waves), each block does ONE 32-row x 512-gate
// tile. Wave w owns j-group w (16 j x 4 gates) and stages A-fragment ks=w
// (convert-on-stage, validated in R7: cvt deduped 8x, bank conflicts 0).
// Weights are STREAMED from L2 per ks (4 frags, 2-deep prefetch), not pinned:
// keeps true reg demand ~116 < 128 so __launch_bounds__(512,4) gives
// 16 waves/CU (2 independent blocks) WITHOUT spilling (R7 spilled: demand 190
// vs cap 128 -> 100 MB scratch traffic). No hand vmcnt: every global load has
// a register destination, compiler emits exact counted waits. Raw
// lgkmcnt(0)+s_barrier keeps in-flight vmem alive across the barrier.

typedef short s16x8 __attribute__((ext_vector_type(8)));
typedef float f32x4 __attribute__((ext_vector_type(4)));

__device__ __forceinline__ short f2bf(float f) {
    __hip_bfloat16 h = __float2bfloat16(f);
    return __builtin_bit_cast(short, h);
}
__device__ __forceinline__ float sigm(float x) { return 1.0f / (1.0f + __expf(-x)); }
__device__ __forceinline__ float tanh_f(float x) { return 1.0f - 2.0f / (1.0f + __expf(2.0f * x)); }

// ---- kernel 1: repack 8 fp32 weight mats -> bf16 MFMA-fragment order ----
// Frag fi = (jt16*4 + g)*8 + ks  (256 frags x 1 KB). Lane l of frag holds
// W[g][j = jt16*16 + (l&15)][k = ks*32 + (l>>4)*8 .. +8), k<128 from W_x,
// k>=128 from W_h (k-128). Element order: v[0..3]=k+0..3, v[4..7]=k+4..7.
__global__ __launch_bounds__(256)
void repack_weights(const float* __restrict__ Wii, const float* __restrict__ Whi,
                    const float* __restrict__ Wif, const float* __restrict__ Whf,
                    const float* __restrict__ Wig, const float* __restrict__ Whg,
                    const float* __restrict__ Wio, const float* __restrict__ Who,
                    short* __restrict__ ws)
{
    const int t   = blockIdx.x * 256 + threadIdx.x;   // 16384 threads
    const int fi  = t >> 6;
    const int l   = t & 63;
    const int ks  = fi & 7;
    const int g   = (fi >> 3) & 3;
    const int jt  = fi >> 5;
    const int j   = jt * 16 + (l & 15);
    const int k   = ks * 32 + (l >> 4) * 8;

    const float* wx = (g == 0) ? Wii : (g == 1) ? Wif : (g == 2) ? Wig : Wio;
    const float* wh = (g == 0) ? Whi : (g == 1) ? Whf : (g == 2) ? Whg : Who;
    const float* src = (k < 128) ? (wx + (size_t)j * 128 + k)
                                 : (wh + (size_t)j * 128 + (k - 128));
    f32x4 a = *(const f32x4*)src;
    f32x4 b = *(const f32x4*)(src + 4);
    s16x8 v;
#pragma unroll
    for (int q = 0; q < 4; ++q) { v[q] = f2bf(a[q]); v[4 + q] = f2bf(b[q]); }
    *(s16x8*)(ws + (size_t)t * 8) = v;
}

// ---- kernel 2: main fused LSTM (one tile per block) ----
__global__ __launch_bounds__(512, 4)
void lstm_cell_kernel(const float* __restrict__ X,
                      const float* __restrict__ H,
                      const float* __restrict__ C,
                      const float* __restrict__ Bi, const float* __restrict__ Bf,
                      const float* __restrict__ Bg, const float* __restrict__ Bo,
                      const short* __restrict__ WS,
                      float* __restrict__ OutH,
                      float* __restrict__ OutC)
{
    __shared__ __align__(16) char sA[16384];   // 16 frags x 1 KB (single buffer)

    const int tid = threadIdx.x;
    const int l   = tid & 63;
    const int w   = tid >> 6;          // 0..7
    const int lj  = l & 15;
    const int lq  = l >> 4;
    const int jw  = w * 16 + lj;       // this lane's j (all 4 gates)
    const int B0  = blockIdx.x * 32;

    // ---- issue A loads for this wave's staged fragment (ks = w) ----
    // frag ks covers k in [ks*32, ks*32+32): ks<4 from X, ks>=4 from H.
    const float* abase = (w < 4) ? X : H;
    const int    colr  = (w & 3) * 32 + lq * 8;
    f32x4 sa[2], sb[2];                // [mt]
#pragma unroll
    for (int mt = 0; mt < 2; ++mt) {
        const float* p = abase + (size_t)(B0 + mt * 16 + lj) * 128 + colr;
        sa[mt] = *(const f32x4*)p;
        sb[mt] = *(const f32x4*)(p + 4);
    }

    // ---- issue weight preload (ks 0,1), C prefetch, biases (all in flight) ----
    const short* wsw = WS + (size_t)(w * 4) * 8 * 512 + (size_t)l * 8;
    s16x8 wbuf[2][4];                  // [parity][g], 2-deep stream buffer
#pragma unroll
    for (int g = 0; g < 4; ++g) {
        wbuf[0][g] = *(const s16x8*)(wsw + (size_t)(g * 8 + 0) * 512);
        wbuf[1][g] = *(const s16x8*)(wsw + (size_t)(g * 8 + 1) * 512);
    }

    float cpv[8];
#pragma unroll
    for (int mt = 0; mt < 2; ++mt)
#pragma unroll
        for (int r = 0; r < 4; ++r)
            cpv[mt * 4 + r] = C[(size_t)(B0 + mt * 16 + lq * 4 + r) * 128 + jw];

    const float bi  = Bi[jw];
    const float bfv = Bf[jw];
    const float bg  = Bg[jw];
    const float bo  = Bo[jw];

    // ---- stage: cvt fp32->bf16, write own frag (compiler waits sa/sb) ----
#pragma unroll
    for (int mt = 0; mt < 2; ++mt) {
        s16x8 v;
#pragma unroll
        for (int q = 0; q < 4; ++q) {
            v[q]     = f2bf(sa[mt][q]);
            v[4 + q] = f2bf(sb[mt][q]);
        }
        *(s16x8*)(sA + (mt * 8 + w) * 1024 + l * 16) = v;
    }
    // own ds_writes retired, then block-wide barrier; vmem stays in flight.
    asm volatile("s_waitcnt lgkmcnt(0)\n\ts_barrier" ::: "memory");

    // ---- K-loop: 8 ks steps, 2-deep weight stream ----
    f32x4 acc[2][4];                   // [mt][g]
#pragma unroll
    for (int mt = 0; mt < 2; ++mt)
#pragma unroll
        for (int g = 0; g < 4; ++g)
            acc[mt][g] = (f32x4){0.f, 0.f, 0.f, 0.f};

#pragma unroll
    for (int ks = 0; ks < 8; ++ks) {
        const s16x8 af0 = *(const s16x8*)(sA + (0 * 8 + ks) * 1024 + l * 16);
        const s16x8 af1 = *(const s16x8*)(sA + (1 * 8 + ks) * 1024 + l * 16);
#pragma unroll
        for (int g = 0; g < 4; ++g) {
            acc[0][g] = __builtin_amdgcn_mfma_f32_16x16x32_bf16(af0, wbuf[ks & 1][g], acc[0][g], 0, 0, 0);
            acc[1][g] = __builtin_amdgcn_mfma_f32_16x16x32_bf16(af1, wbuf[ks & 1][g], acc[1][g], 0, 0, 0);
        }
        if (ks < 6) {                  // refill consumed buffer with ks+2
#pragma unroll
            for (int g = 0; g < 4; ++g)
                wbuf[ks & 1][g] = *(const s16x8*)(wsw + (size_t)(g * 8 + ks + 2) * 512);
        }
    }

    // ---- epilogue: all 4 gates of (b,j) in-lane; C from prefetch ----
#pragma unroll
    for (int mt = 0; mt < 2; ++mt) {
#pragma unroll
        for (int r = 0; r < 4; ++r) {
            const int b = B0 + mt * 16 + lq * 4 + r;   // C/D: row=(lane>>4)*4+reg
            const size_t idx = (size_t)b * 128 + jw;
            const float ia = acc[mt][0][r] + bi;
            const float fa = acc[mt][1][r] + bfv;
            const float ga = acc[mt][2][r] + bg;
            const float oa = acc[mt][3][r] + bo;
            const float it = sigm(ia);
            const float ft = sigm(fa);
            const float gt = tanh_f(ga);
            const float ot = sigm(oa);
            const float co = cpv[mt * 4 + r];
            const float cn = ft * co + it * gt;
            const float hn = ot * tanh_f(cn);
            OutH[idx] = hn;
            OutC[idx] = cn;
        }
    }
}

extern "C" void kernel_launch(void* const* d_in, const int* in_sizes, int n_in,
                              void* d_out, int out_size, void* d_ws, size_t ws_size,
                              hipStream_t stream) {
    const float* X   = (const float*)d_in[0];
    const float* H   = (const float*)d_in[1];
    const float* C   = (const float*)d_in[2];
    const float* Wii = (const float*)d_in[3];
    const float* Whi = (const float*)d_in[4];
    const float* Bi  = (const float*)d_in[5];
    const float* Wif = (const float*)d_in[6];
    const float* Whf = (const float*)d_in[7];
    const float* Bf  = (const float*)d_in[8];
    const float* Wig = (const float*)d_in[9];
    const float* Whg = (const float*)d_in[10];
    const float* Bg  = (const float*)d_in[11];
    const float* Wio = (const float*)d_in[12];
    const float* Who = (const float*)d_in[13];
    const float* Bo  = (const float*)d_in[14];

    short* ws = (short*)d_ws;   // 256 KB bf16 fragment-ordered weights

    hipLaunchKernelGGL(repack_weights, dim3(64), dim3(256), 0, stream,
                       Wii, Whi, Wif, Whf, Wig, Whg, Wio, Who, ws);

    float* OutH = (float*)d_out;
    float* OutC = OutH + (size_t)65536 * 128;

    hipLaunchKernelGGL(lstm_cell_kernel, dim3(2048), dim3(512), 0, stream,
                       X, H, C, Bi, Bf, Bg, Bo, ws, OutH, OutC);
}